// Round 1
// baseline (362.602 us; speedup 1.0000x reference)
//
#include <hip/hip_runtime.h>
#include <hip/hip_bf16.h>

typedef __bf16 bf16;
typedef __attribute__((ext_vector_type(8))) __bf16 bf16x8;
typedef __attribute__((ext_vector_type(4))) float f32x4;

#define MFMA16(a, b, c) __builtin_amdgcn_mfma_f32_16x16x32_bf16((a), (b), (c), 0, 0, 0)

constexpr int Bn = 2, Tn = 2048, Cn = 1024, Hn = 16, Dn = 64;
constexpr int Mn = Bn * Tn;        // 4096 rows for all projection GEMMs
constexpr int WSZ = Cn * Cn;       // 1M elements per weight
constexpr int XSZ = Mn * Cn;       // 4.19M elements per activation

struct GemmArgs {
  const void* A[3];
  const bf16* Bt[3];
  const float* bias[3];
  void* out[3];
  float scale[3];
};

// ---------------- W[k][n] fp32 -> Wt[n][k] bf16 ----------------
__global__ __launch_bounds__(256) void transpose_convert(const float* __restrict__ W,
                                                         bf16* __restrict__ Wt) {
  __shared__ float tile[32][33];
  const int tx = threadIdx.x, ty = threadIdx.y;  // (32,8)
  const int x = blockIdx.x * 32 + tx;
  const int y0 = blockIdx.y * 32;
  for (int j = 0; j < 32; j += 8) tile[ty + j][tx] = W[(y0 + ty + j) * Cn + x];
  __syncthreads();
  const int n0 = blockIdx.x * 32;
  const int k = blockIdx.y * 32 + tx;
  for (int j = 0; j < 32; j += 8)
    Wt[(n0 + ty + j) * Cn + k] = (bf16)tile[tx][ty + j];
}

// ---------------- GEMM: C[M,N] = A[M,K] @ Wt[N,K]^T + bias ----------------
// 128x128 block tile, BK=64, 4 waves each computing 64x64 (4x4 MFMA tiles).
template <bool A_IS_F32, bool SPLIT_OUT>
__global__ __launch_bounds__(256) void gemm_kernel(GemmArgs args, int M, int N, int K) {
  const int z = blockIdx.z;
  const bf16* __restrict__ Bt = args.Bt[z];
  const float* __restrict__ bias = args.bias[z];
  const float scale = args.scale[z];

  __shared__ bf16 As[128 * 64];
  __shared__ bf16 Bs[128 * 64];

  const int tid = threadIdx.x;
  const int w = tid >> 6, lane = tid & 63;
  const int wm = w >> 1, wn = w & 1;
  const int g = lane >> 4, l15 = lane & 15;
  const int m0 = blockIdx.y * 128, n0 = blockIdx.x * 128;

  f32x4 acc[4][4] = {};

  for (int k0 = 0; k0 < K; k0 += 64) {
    if (k0) __syncthreads();
    // stage A tile (128 x 64)
    if constexpr (A_IS_F32) {
      const float* __restrict__ A = (const float*)args.A[z];
      for (int i = 0; i < 8; i++) {
        int e = i * 256 + tid;
        int row = e >> 4, c4 = (e & 15) << 2;
        float4 v = *(const float4*)&A[(size_t)(m0 + row) * K + k0 + c4];
        bf16* d = &As[row * 64 + c4];
        d[0] = (bf16)v.x; d[1] = (bf16)v.y; d[2] = (bf16)v.z; d[3] = (bf16)v.w;
      }
    } else {
      const bf16* __restrict__ A = (const bf16*)args.A[z];
      for (int i = 0; i < 4; i++) {
        int e = i * 256 + tid;
        int row = e >> 3, c8 = (e & 7) << 3;
        *(uint4*)&As[row * 64 + c8] = *(const uint4*)&A[(size_t)(m0 + row) * K + k0 + c8];
      }
    }
    // stage B tile (128 x 64) from Wt[n][k]
    for (int i = 0; i < 4; i++) {
      int e = i * 256 + tid;
      int row = e >> 3, c8 = (e & 7) << 3;
      *(uint4*)&Bs[row * 64 + c8] = *(const uint4*)&Bt[(size_t)(n0 + row) * K + k0 + c8];
    }
    __syncthreads();

    for (int ks = 0; ks < 2; ks++) {
      bf16x8 af[4], bfr[4];
      for (int mt = 0; mt < 4; mt++)
        af[mt] = *(const bf16x8*)&As[(wm * 64 + mt * 16 + l15) * 64 + ks * 32 + g * 8];
      for (int nt = 0; nt < 4; nt++)
        bfr[nt] = *(const bf16x8*)&Bs[(wn * 64 + nt * 16 + l15) * 64 + ks * 32 + g * 8];
      for (int mt = 0; mt < 4; mt++)
        for (int nt = 0; nt < 4; nt++)
          acc[mt][nt] = MFMA16(af[mt], bfr[nt], acc[mt][nt]);
    }
  }

  // epilogue: C/D layout row=(lane>>4)*4+r, col=lane&15
  for (int mt = 0; mt < 4; mt++) {
    for (int nt = 0; nt < 4; nt++) {
      int gn = n0 + wn * 64 + nt * 16 + l15;
      float bb = bias[gn];
      for (int r = 0; r < 4; r++) {
        int gm = m0 + wm * 64 + mt * 16 + g * 4 + r;
        float v = (acc[mt][nt][r] + bb) * scale;
        if constexpr (SPLIT_OUT) {
          // out bf16 in [B,H,T,D]
          int b = gm >> 11, t = gm & 2047, h = gn >> 6, d = gn & 63;
          ((bf16*)args.out[z])[(size_t)((b * Hn + h) * Tn + t) * Dn + d] = (bf16)v;
        } else {
          ((float*)args.out[z])[(size_t)gm * N + gn] = v;
        }
      }
    }
  }
}

// ---------------- Flash attention: per (b,h), 128 Q rows per block ----------------
__global__ __launch_bounds__(256) void attn_kernel(const bf16* __restrict__ Qh,
                                                   const bf16* __restrict__ Kh,
                                                   const bf16* __restrict__ Vh,
                                                   bf16* __restrict__ AO) {
  __shared__ bf16 Qs[128 * 64];  // reused as Ps after q-frags are in registers
  __shared__ bf16 Ks[64 * 64];   // [t'][d]
  __shared__ bf16 Vs[64 * 64];   // transposed: [d][t']

  const int tid = threadIdx.x;
  const int w = tid >> 6, lane = tid & 63;
  const int g = lane >> 4, l15 = lane & 15;
  const int bh = blockIdx.y;       // b*16 + h
  const int q0 = blockIdx.x * 128;
  const size_t hb = (size_t)bh * Tn * Dn;

  // stage Q tile 128x64
  for (int i = 0; i < 4; i++) {
    int e = i * 256 + tid;
    int row = e >> 3, c8 = (e & 7) << 3;
    *(uint4*)&Qs[row * 64 + c8] = *(const uint4*)&Qh[hb + (size_t)(q0 + row) * Dn + c8];
  }
  __syncthreads();

  // preload Q fragments (A-layout: m=lane&15, k=g*8+j), rows w*32 + mt*16 + m
  bf16x8 qf[2][2];
  for (int mt = 0; mt < 2; mt++)
    for (int ks = 0; ks < 2; ks++)
      qf[mt][ks] = *(const bf16x8*)&Qs[(w * 32 + mt * 16 + l15) * 64 + ks * 32 + g * 8];

  f32x4 O[2][4] = {};
  float mrow[2][4], lrow[2][4];
  for (int mt = 0; mt < 2; mt++)
    for (int r = 0; r < 4; r++) { mrow[mt][r] = -1e30f; lrow[mt][r] = 0.f; }

  bf16* Ps = Qs;

  for (int kt = 0; kt < Tn / 64; kt++) {
    __syncthreads();  // prev iter's reads of Ks/Vs/Ps done; Qs frag reads done (iter 0)
    const int t0 = kt * 64;
    // stage K tile 64x64 ([t'][d])
    for (int i = 0; i < 2; i++) {
      int e = i * 256 + tid;
      int row = e >> 3, c8 = (e & 7) << 3;
      *(uint4*)&Ks[row * 64 + c8] = *(const uint4*)&Kh[hb + (size_t)(t0 + row) * Dn + c8];
    }
    // stage V tile transposed -> Vs[d][t']
    for (int i = 0; i < 2; i++) {
      int e = i * 256 + tid;
      int tv = e & 63, d8 = (e >> 6) << 3;
      uint4 raw = *(const uint4*)&Vh[hb + (size_t)(t0 + tv) * Dn + d8];
      const bf16* pv = (const bf16*)&raw;
      for (int j = 0; j < 8; j++) Vs[(d8 + j) * 64 + tv] = pv[j];
    }
    __syncthreads();

    // S = Q K^T : 2 m-tiles x 4 n-tiles x 2 k-steps
    f32x4 s[2][4] = {};
    bf16x8 kf[4][2];
    for (int nt = 0; nt < 4; nt++)
      for (int ks = 0; ks < 2; ks++)
        kf[nt][ks] = *(const bf16x8*)&Ks[(nt * 16 + l15) * 64 + ks * 32 + g * 8];
    for (int mt = 0; mt < 2; mt++)
      for (int nt = 0; nt < 4; nt++)
        for (int ks = 0; ks < 2; ks++)
          s[mt][nt] = MFMA16(qf[mt][ks], kf[nt][ks], s[mt][nt]);

    // online softmax (row = mt*16 + g*4 + r, held across 16 lanes l15)
    for (int mt = 0; mt < 2; mt++) {
      for (int r = 0; r < 4; r++) {
        float mx = fmaxf(fmaxf(s[mt][0][r], s[mt][1][r]), fmaxf(s[mt][2][r], s[mt][3][r]));
        for (int off = 1; off < 16; off <<= 1) mx = fmaxf(mx, __shfl_xor(mx, off, 16));
        float mn = fmaxf(mrow[mt][r], mx);
        float alpha = __expf(mrow[mt][r] - mn);
        mrow[mt][r] = mn;
        float rs = 0.f;
        for (int nt = 0; nt < 4; nt++) {
          float p = __expf(s[mt][nt][r] - mn);
          s[mt][nt][r] = p;
          rs += p;
        }
        for (int off = 1; off < 16; off <<= 1) rs += __shfl_xor(rs, off, 16);
        lrow[mt][r] = lrow[mt][r] * alpha + rs;
        for (int dt = 0; dt < 4; dt++) O[mt][dt][r] *= alpha;
        // write P to per-wave Ps region (C-layout -> LDS row-major)
        for (int nt = 0; nt < 4; nt++)
          Ps[w * 2048 + (mt * 16 + g * 4 + r) * 64 + nt * 16 + l15] = (bf16)s[mt][nt][r];
      }
    }
    __syncthreads();  // Ps visible; Vs still valid

    // O += P @ V  (P from Ps in A-layout; V from transposed Vs)
    for (int mt = 0; mt < 2; mt++) {
      for (int ks = 0; ks < 2; ks++) {
        bf16x8 pf = *(const bf16x8*)&Ps[w * 2048 + (mt * 16 + l15) * 64 + ks * 32 + g * 8];
        for (int dt = 0; dt < 4; dt++) {
          bf16x8 vf = *(const bf16x8*)&Vs[(dt * 16 + l15) * 64 + ks * 32 + g * 8];
          O[mt][dt] = MFMA16(pf, vf, O[mt][dt]);
        }
      }
    }
  }

  // epilogue: AO[b*T + t][h*64 + d] bf16
  const int b = bh >> 4, h = bh & 15;
  for (int mt = 0; mt < 2; mt++) {
    for (int r = 0; r < 4; r++) {
      float inv = 1.0f / lrow[mt][r];
      int t = q0 + w * 32 + mt * 16 + g * 4 + r;
      for (int dt = 0; dt < 4; dt++) {
        AO[(size_t)(b * Tn + t) * Cn + h * Dn + dt * 16 + l15] = (bf16)(O[mt][dt][r] * inv);
      }
    }
  }
}

extern "C" void kernel_launch(void* const* d_in, const int* in_sizes, int n_in,
                              void* d_out, int out_size, void* d_ws, size_t ws_size,
                              hipStream_t stream) {
  const float* query = (const float*)d_in[0];
  const float* key   = (const float*)d_in[1];
  const float* value = (const float*)d_in[2];
  const float* Wq = (const float*)d_in[3];
  const float* bq = (const float*)d_in[4];
  const float* Wk = (const float*)d_in[5];
  const float* bk = (const float*)d_in[6];
  const float* Wv = (const float*)d_in[7];
  const float* bv = (const float*)d_in[8];
  const float* Wo = (const float*)d_in[9];
  const float* bo = (const float*)d_in[10];

  bf16* p = (bf16*)d_ws;
  bf16* WqT = p; p += WSZ;
  bf16* WkT = p; p += WSZ;
  bf16* WvT = p; p += WSZ;
  bf16* WoT = p; p += WSZ;
  bf16* Qh = p; p += XSZ;
  bf16* Kh = p; p += XSZ;
  bf16* Vh = p; p += XSZ;
  bf16* AO = p; p += XSZ;

  dim3 tb(32, 8), tg(32, 32);
  transpose_convert<<<tg, tb, 0, stream>>>(Wq, WqT);
  transpose_convert<<<tg, tb, 0, stream>>>(Wk, WkT);
  transpose_convert<<<tg, tb, 0, stream>>>(Wv, WvT);
  transpose_convert<<<tg, tb, 0, stream>>>(Wo, WoT);

  GemmArgs ga;
  ga.A[0] = query; ga.A[1] = key; ga.A[2] = value;
  ga.Bt[0] = WqT;  ga.Bt[1] = WkT; ga.Bt[2] = WvT;
  ga.bias[0] = bq; ga.bias[1] = bk; ga.bias[2] = bv;
  ga.out[0] = Qh;  ga.out[1] = Kh;  ga.out[2] = Vh;
  ga.scale[0] = 0.125f; ga.scale[1] = 1.0f; ga.scale[2] = 1.0f;  // fold 1/sqrt(D) into Q
  gemm_kernel<true, true><<<dim3(Cn / 128, Mn / 128, 3), 256, 0, stream>>>(ga, Mn, Cn, Cn);

  attn_kernel<<<dim3(Tn / 128, Bn * Hn), 256, 0, stream>>>(Qh, Kh, Vh, AO);

  GemmArgs gb;
  gb.A[0] = AO; gb.Bt[0] = WoT; gb.bias[0] = bo; gb.out[0] = d_out; gb.scale[0] = 1.0f;
  gb.A[1] = gb.A[2] = nullptr; gb.Bt[1] = gb.Bt[2] = nullptr;
  gb.bias[1] = gb.bias[2] = nullptr; gb.out[1] = gb.out[2] = nullptr;
  gb.scale[1] = gb.scale[2] = 1.0f;
  gemm_kernel<false, false><<<dim3(Cn / 128, Mn / 128, 1), 256, 0, stream>>>(gb, Mn, Cn, Cn);
}

// Round 2
// 313.918 us; speedup vs baseline: 1.1551x; 1.1551x over previous
//
#include <hip/hip_runtime.h>
#include <hip/hip_bf16.h>

typedef __bf16 bf16;
typedef __attribute__((ext_vector_type(8))) __bf16 bf16x8;
typedef __attribute__((ext_vector_type(4))) __bf16 bf16x4;
typedef __attribute__((ext_vector_type(2))) __bf16 bf16x2;
typedef __attribute__((ext_vector_type(4))) float f32x4;

#define MFMA16(a, b, c) __builtin_amdgcn_mfma_f32_16x16x32_bf16((a), (b), (c), 0, 0, 0)

constexpr int Bn = 2, Tn = 2048, Cn = 1024, Hn = 16, Dn = 64;
constexpr int Mn = Bn * Tn;        // 4096 rows for all projection GEMMs
constexpr int WSZ = Cn * Cn;       // 1M elements per weight
constexpr int XSZ = Mn * Cn;       // 4.19M elements per activation
constexpr float LOG2E = 1.44269504088896f;

// async global->LDS, 16B per lane: LDS dest = base + lane*16 (wave-uniform base)
__device__ __forceinline__ void async_cp16(bf16* lds, const bf16* g) {
  __builtin_amdgcn_global_load_lds(
      (const __attribute__((address_space(1))) unsigned int*)g,
      (__attribute__((address_space(3))) unsigned int*)lds, 16, 0, 0);
}

struct GemmArgs {
  const void* A[3];
  const bf16* Bt[3];
  const float* bias[3];
  void* out[3];
  float scale[3];
};

struct TransArgs {
  const float* W[4];
  bf16* Wt[4];
};

// ---------------- W[k][n] fp32 -> Wt[n][k] bf16 (4 weights via grid.z) ----------------
__global__ __launch_bounds__(256) void transpose_convert(TransArgs ta) {
  const float* __restrict__ W = ta.W[blockIdx.z];
  bf16* __restrict__ Wt = ta.Wt[blockIdx.z];
  __shared__ float tile[32][33];
  const int tx = threadIdx.x, ty = threadIdx.y;  // (32,8)
  const int x = blockIdx.x * 32 + tx;
  const int y0 = blockIdx.y * 32;
  for (int j = 0; j < 32; j += 8) tile[ty + j][tx] = W[(y0 + ty + j) * Cn + x];
  __syncthreads();
  const int n0 = blockIdx.x * 32;
  const int k = blockIdx.y * 32 + tx;
  for (int j = 0; j < 32; j += 8)
    Wt[(n0 + ty + j) * Cn + k] = (bf16)tile[tx][ty + j];
}

// ---------------- GEMM: C[M,N] = A[M,K] @ Wt[N,K]^T + bias ----------------
// 128x128 block tile, BK=64, 4 waves each 64x64 (4x4 MFMA tiles).
// B staged via global_load_lds(16B); A likewise when bf16, else f32->bf16 during staging.
template <bool A_IS_F32, bool SPLIT_OUT>
__global__ __launch_bounds__(256) void gemm_kernel(GemmArgs args, int M, int N, int K) {
  const int z = blockIdx.z;
  const bf16* __restrict__ Bt = args.Bt[z];
  const float* __restrict__ bias = args.bias[z];
  const float scale = args.scale[z];

  __shared__ bf16 As[128 * 64];
  __shared__ bf16 Bs[128 * 64];

  const int tid = threadIdx.x;
  const int w = tid >> 6, lane = tid & 63;
  const int wm = w >> 1, wn = w & 1;
  const int g = lane >> 4, l15 = lane & 15;
  const int m0 = blockIdx.y * 128, n0 = blockIdx.x * 128;

  f32x4 acc[4][4] = {};

  for (int k0 = 0; k0 < K; k0 += 64) {
    __syncthreads();  // previous iteration's frag reads done
    // stage A tile (128 x 64)
    if constexpr (A_IS_F32) {
      const float* __restrict__ A = (const float*)args.A[z];
      for (int i = 0; i < 8; i++) {
        int e = i * 256 + tid;
        int row = e >> 4, c4 = (e & 15) << 2;
        float4 v = *(const float4*)&A[(size_t)(m0 + row) * K + k0 + c4];
        bf16x4 ov = {(bf16)v.x, (bf16)v.y, (bf16)v.z, (bf16)v.w};
        *(bf16x4*)&As[row * 64 + c4] = ov;
      }
    } else {
      const bf16* __restrict__ A = (const bf16*)args.A[z];
      for (int i = 0; i < 4; i++) {
        int p = w * 4 + i;  // 1KB chunk = 8 rows of 128B
        async_cp16(&As[p * 512],
                   &A[(size_t)(m0 + p * 8 + (lane >> 3)) * K + k0 + ((lane & 7) << 3)]);
      }
    }
    // stage B tile (128 x 64) from Wt[n][k]
    for (int i = 0; i < 4; i++) {
      int p = w * 4 + i;
      async_cp16(&Bs[p * 512],
                 &Bt[(size_t)(n0 + p * 8 + (lane >> 3)) * K + k0 + ((lane & 7) << 3)]);
    }
    __syncthreads();  // barrier drains vmcnt -> LDS visible

    for (int ks = 0; ks < 2; ks++) {
      bf16x8 af[4], bfr[4];
      for (int mt = 0; mt < 4; mt++)
        af[mt] = *(const bf16x8*)&As[(wm * 64 + mt * 16 + l15) * 64 + ks * 32 + g * 8];
      for (int nt = 0; nt < 4; nt++)
        bfr[nt] = *(const bf16x8*)&Bs[(wn * 64 + nt * 16 + l15) * 64 + ks * 32 + g * 8];
      for (int mt = 0; mt < 4; mt++)
        for (int nt = 0; nt < 4; nt++)
          acc[mt][nt] = MFMA16(af[mt], bfr[nt], acc[mt][nt]);
    }
  }

  // epilogue: C/D layout row=(lane>>4)*4+r, col=lane&15
  for (int mt = 0; mt < 4; mt++) {
    for (int nt = 0; nt < 4; nt++) {
      int gn = n0 + wn * 64 + nt * 16 + l15;
      float bb = bias[gn];
      for (int r = 0; r < 4; r++) {
        int gm = m0 + wm * 64 + mt * 16 + g * 4 + r;
        float v = (acc[mt][nt][r] + bb) * scale;
        if constexpr (SPLIT_OUT) {
          // out bf16 in [B,H,T,D]
          int b = gm >> 11, t = gm & 2047, h = gn >> 6, d = gn & 63;
          ((bf16*)args.out[z])[(size_t)((b * Hn + h) * Tn + t) * Dn + d] = (bf16)v;
        } else {
          ((float*)args.out[z])[(size_t)gm * N + gn] = v;
        }
      }
    }
  }
}

// ---------------- Flash attention v2: S^T = K Q^T, O^T = V^T P^T ----------------
// Block: 64 Q rows (4 waves x 16), KV tile 64. 1024 blocks. LDS ~25.6KB -> ~6 blocks/CU.
// Softmax axis (kv) lands on regs+g-groups: in-register reduction + 2 shuffles.
constexpr int LDP = 72;  // Pt row stride: mult of 8 (b128-aligned reads), <=4-way write conflicts

__global__ __launch_bounds__(256) void attn_kernel(const bf16* __restrict__ Qh,
                                                   const bf16* __restrict__ Kh,
                                                   const bf16* __restrict__ Vh,
                                                   bf16* __restrict__ AO) {
  __shared__ bf16 Ks[64 * 64];   // [kv][d]
  __shared__ bf16 Vt[64 * 64];   // [d][kv]
  __shared__ bf16 Pt[64 * LDP];  // [q][kv], wave-private rows, no barrier needed

  const int tid = threadIdx.x;
  const int w = tid >> 6, lane = tid & 63;
  const int g = lane >> 4, l15 = lane & 15;
  const int bh = blockIdx.y;       // b*16 + h
  const int q0 = blockIdx.x * 64;
  const size_t hb = (size_t)bh * Tn * Dn;
  const int qrow = q0 + w * 16 + l15;  // this lane's Q row (= S^T column)

  // Q fragments straight from global (B-operand of S^T = A-layout regs of Q)
  bf16x8 qf[2];
  {
    const bf16* qp = Qh + hb + (size_t)qrow * Dn + g * 8;
    qf[0] = *(const bf16x8*)qp;
    qf[1] = *(const bf16x8*)(qp + 32);
  }

  f32x4 o[4] = {};                  // O^T accum: row=d (g*4+r within dt*16), col=q=l15
  float m_run = -1e30f, l_run = 0.f;
  bf16* prow = &Pt[(w * 16 + l15) * LDP];

  for (int kt = 0; kt < Tn / 64; kt++) {
    const int t0 = kt * 64;
    __syncthreads();  // all waves done reading Ks/Vt of previous tile
    // stage K tile [kv][d] via async 16B copies (tile is contiguous in global)
    for (int i = 0; i < 2; i++) {
      int p = w * 2 + i;
      async_cp16(&Ks[p * 512],
                 &Kh[hb + (size_t)(t0 + p * 8 + (lane >> 3)) * Dn + ((lane & 7) << 3)]);
    }
    // stage V transposed -> Vt[d][kv] (conflict-free: lanes write consecutive tv)
    for (int i = 0; i < 2; i++) {
      int e = i * 256 + tid;
      int tv = e & 63, d8 = (e >> 6) << 3;
      uint4 raw = *(const uint4*)&Vh[hb + (size_t)(t0 + tv) * Dn + d8];
      const bf16* pv = (const bf16*)&raw;
      for (int j = 0; j < 8; j++) Vt[(d8 + j) * 64 + tv] = pv[j];
    }
    __syncthreads();

    // S^T[kv][q] = K Q^T : A = K-frag, B = Q-frag. 4 kv-tiles x 2 k-steps.
    f32x4 s[4] = {};
    for (int nt = 0; nt < 4; nt++) {
      const bf16* kp = &Ks[(nt * 16 + l15) * 64 + g * 8];
      bf16x8 kf0 = *(const bf16x8*)kp;
      bf16x8 kf1 = *(const bf16x8*)(kp + 32);
      s[nt] = MFMA16(kf0, qf[0], s[nt]);
      s[nt] = MFMA16(kf1, qf[1], s[nt]);
    }

    // online softmax over kv (= regs nt,r + lane-groups g): per-lane scalar stats
    float mx = s[0][0];
    for (int nt = 0; nt < 4; nt++)
      for (int r = 0; r < 4; r++) mx = fmaxf(mx, s[nt][r]);
    mx = fmaxf(mx, __shfl_xor(mx, 16));
    mx = fmaxf(mx, __shfl_xor(mx, 32));
    float mn = fmaxf(m_run, mx);
    float alpha = exp2f(m_run - mn);  // log2e folded into Q scale
    float rs = 0.f;
    for (int nt = 0; nt < 4; nt++)
      for (int r = 0; r < 4; r++) {
        float pe = exp2f(s[nt][r] - mn);
        s[nt][r] = pe;
        rs += pe;
      }
    rs += __shfl_xor(rs, 16);
    rs += __shfl_xor(rs, 32);
    l_run = l_run * alpha + rs;
    m_run = mn;
    for (int dt = 0; dt < 4; dt++) o[dt] = o[dt] * alpha;

    // P -> Pt[q][kv] (packed b32 writes; kv = nt*16 + g*4 + r)
    for (int nt = 0; nt < 4; nt++) {
      bf16x2 p0 = {(bf16)s[nt][0], (bf16)s[nt][1]};
      bf16x2 p1 = {(bf16)s[nt][2], (bf16)s[nt][3]};
      *(bf16x2*)&prow[nt * 16 + g * 4] = p0;
      *(bf16x2*)&prow[nt * 16 + g * 4 + 2] = p1;
    }

    // O^T += V^T P^T : A = V^T-frag (from Vt), B = P-frag (from Pt row, contiguous kv)
    for (int ks = 0; ks < 2; ks++) {
      bf16x8 pf = *(const bf16x8*)&prow[ks * 32 + g * 8];
      for (int dt = 0; dt < 4; dt++) {
        bf16x8 vf = *(const bf16x8*)&Vt[(dt * 16 + l15) * 64 + ks * 32 + g * 8];
        o[dt] = MFMA16(vf, pf, o[dt]);
      }
    }
  }

  // epilogue: lane owns one q row entirely; d = dt*16 + g*4 + r
  const int b = bh >> 4, h = bh & 15;
  float inv = 1.0f / l_run;
  bf16* orow = AO + (size_t)(b * Tn + qrow) * Cn + h * Dn;
  for (int dt = 0; dt < 4; dt++) {
    bf16x4 ov = {(bf16)(o[dt][0] * inv), (bf16)(o[dt][1] * inv),
                 (bf16)(o[dt][2] * inv), (bf16)(o[dt][3] * inv)};
    *(bf16x4*)&orow[dt * 16 + g * 4] = ov;
  }
}

extern "C" void kernel_launch(void* const* d_in, const int* in_sizes, int n_in,
                              void* d_out, int out_size, void* d_ws, size_t ws_size,
                              hipStream_t stream) {
  const float* query = (const float*)d_in[0];
  const float* key   = (const float*)d_in[1];
  const float* value = (const float*)d_in[2];
  const float* Wq = (const float*)d_in[3];
  const float* bq = (const float*)d_in[4];
  const float* Wk = (const float*)d_in[5];
  const float* bk = (const float*)d_in[6];
  const float* Wv = (const float*)d_in[7];
  const float* bv = (const float*)d_in[8];
  const float* Wo = (const float*)d_in[9];
  const float* bo = (const float*)d_in[10];

  bf16* p = (bf16*)d_ws;
  bf16* WqT = p; p += WSZ;
  bf16* WkT = p; p += WSZ;
  bf16* WvT = p; p += WSZ;
  bf16* WoT = p; p += WSZ;
  bf16* Qh = p; p += XSZ;
  bf16* Kh = p; p += XSZ;
  bf16* Vh = p; p += XSZ;
  bf16* AO = p; p += XSZ;

  TransArgs ta;
  ta.W[0] = Wq; ta.W[1] = Wk; ta.W[2] = Wv; ta.W[3] = Wo;
  ta.Wt[0] = WqT; ta.Wt[1] = WkT; ta.Wt[2] = WvT; ta.Wt[3] = WoT;
  transpose_convert<<<dim3(32, 32, 4), dim3(32, 8), 0, stream>>>(ta);

  GemmArgs ga;
  ga.A[0] = query; ga.A[1] = key; ga.A[2] = value;
  ga.Bt[0] = WqT;  ga.Bt[1] = WkT; ga.Bt[2] = WvT;
  ga.bias[0] = bq; ga.bias[1] = bk; ga.bias[2] = bv;
  ga.out[0] = Qh;  ga.out[1] = Kh;  ga.out[2] = Vh;
  // fold 1/sqrt(D) * log2(e) into Q so softmax can use exp2
  ga.scale[0] = 0.125f * LOG2E; ga.scale[1] = 1.0f; ga.scale[2] = 1.0f;
  gemm_kernel<true, true><<<dim3(Cn / 128, Mn / 128, 3), 256, 0, stream>>>(ga, Mn, Cn, Cn);

  attn_kernel<<<dim3(Tn / 64, Bn * Hn), 256, 0, stream>>>(Qh, Kh, Vh, AO);

  GemmArgs gb;
  gb.A[0] = AO; gb.Bt[0] = WoT; gb.bias[0] = bo; gb.out[0] = d_out; gb.scale[0] = 1.0f;
  gb.A[1] = gb.A[2] = nullptr; gb.Bt[1] = gb.Bt[2] = nullptr;
  gb.bias[1] = gb.bias[2] = nullptr; gb.out[1] = gb.out[2] = nullptr;
  gb.scale[1] = gb.scale[2] = 1.0f;
  gemm_kernel<false, false><<<dim3(Cn / 128, Mn / 128, 1), 256, 0, stream>>>(gb, Mn, Cn, Cn);
}

// Round 3
// 280.038 us; speedup vs baseline: 1.2948x; 1.1210x over previous
//
#include <hip/hip_runtime.h>
#include <hip/hip_bf16.h>

typedef __bf16 bf16;
typedef __attribute__((ext_vector_type(8))) __bf16 bf16x8;
typedef __attribute__((ext_vector_type(4))) __bf16 bf16x4;
typedef __attribute__((ext_vector_type(2))) __bf16 bf16x2;
typedef __attribute__((ext_vector_type(4))) float f32x4;

#define MFMA16(a, b, c) __builtin_amdgcn_mfma_f32_16x16x32_bf16((a), (b), (c), 0, 0, 0)

constexpr int Bn = 2, Tn = 2048, Cn = 1024, Hn = 16, Dn = 64;
constexpr int Mn = Bn * Tn;
constexpr int WSZ = Cn * Cn;
constexpr int XSZ = Mn * Cn;
constexpr float LOG2E = 1.44269504088896f;

// async global->LDS, 16B/lane: LDS dest = wave-uniform base + lane*16
__device__ __forceinline__ void async_cp16(bf16* lds, const bf16* g) {
  __builtin_amdgcn_global_load_lds(
      (const __attribute__((address_space(1))) unsigned int*)g,
      (__attribute__((address_space(3))) unsigned int*)lds, 16, 0, 0);
}

struct GemmArgs {
  const bf16* A[3];
  const bf16* Bt[3];
  const float* bias[3];
  void* out[3];
  float scale[3];
};

struct TransArgs {
  const float* W[4];
  bf16* Wt[4];
};

struct ConvArgs {
  const float* src[3];
};

// ---------------- fp32 -> bf16 bulk convert (query/key/value) ----------------
__global__ __launch_bounds__(256) void convert_bf16(ConvArgs ca, bf16* __restrict__ dst) {
  const int z = blockIdx.y;
  const float* __restrict__ s = ca.src[z];
  size_t idx = ((size_t)blockIdx.x * 256 + threadIdx.x) * 8;
  float4 a = *(const float4*)&s[idx];
  float4 b = *(const float4*)&s[idx + 4];
  bf16x8 o = {(bf16)a.x, (bf16)a.y, (bf16)a.z, (bf16)a.w,
              (bf16)b.x, (bf16)b.y, (bf16)b.z, (bf16)b.w};
  *(bf16x8*)&dst[(size_t)z * XSZ + idx] = o;
}

// ---------------- W[k][n] fp32 -> Wt[n][k] bf16 (4 weights via grid.z) ----------------
__global__ __launch_bounds__(256) void transpose_convert(TransArgs ta) {
  const float* __restrict__ W = ta.W[blockIdx.z];
  bf16* __restrict__ Wt = ta.Wt[blockIdx.z];
  __shared__ float tile[32][33];
  const int tx = threadIdx.x, ty = threadIdx.y;  // (32,8)
  const int x = blockIdx.x * 32 + tx;
  const int y0 = blockIdx.y * 32;
  for (int j = 0; j < 32; j += 8) tile[ty + j][tx] = W[(y0 + ty + j) * Cn + x];
  __syncthreads();
  const int n0 = blockIdx.x * 32;
  const int k = blockIdx.y * 32 + tx;
  for (int j = 0; j < 32; j += 8)
    Wt[(n0 + ty + j) * Cn + k] = (bf16)tile[tx][ty + j];
}

// ---------------- GEMM: C[M,N] = A[M,K] @ Wt[N,K]^T + bias ----------------
// 128x128 tile, BK=64, async 16B staging with XOR-swizzled source so that
// LDS chunk c of row r sits at position c^(r&7)  -> conflict-free b128 frag reads.
template <bool SPLIT_OUT>
__global__ __launch_bounds__(256) void gemm_kernel(GemmArgs args, int K) {
  const int z = blockIdx.z;
  const bf16* __restrict__ A = args.A[z];
  const bf16* __restrict__ Bt = args.Bt[z];
  const float* __restrict__ bias = args.bias[z];
  const float scale = args.scale[z];

  __shared__ bf16 As[128 * 64];
  __shared__ bf16 Bs[128 * 64];

  const int tid = threadIdx.x;
  const int w = tid >> 6, lane = tid & 63;
  const int wm = w >> 1, wn = w & 1;
  const int g = lane >> 4, l15 = lane & 15;
  const int r8 = lane >> 3, c8 = lane & 7;
  const int soff = (c8 ^ r8) << 3;             // swizzled source column offset (elems)
  const int kk = l15 & 7;
  const int off0 = (g ^ kk) << 3;              // ks=0 frag offset within row
  const int off1 = ((4 + g) ^ kk) << 3;        // ks=1
  const int m0 = blockIdx.y * 128, n0 = blockIdx.x * 128;

  f32x4 acc[4][4] = {};

  for (int k0 = 0; k0 < K; k0 += 64) {
    __syncthreads();
    for (int i = 0; i < 4; i++) {
      int p = w * 4 + i;  // 8 rows per async inst
      async_cp16(&As[p * 512], &A[(size_t)(m0 + p * 8 + r8) * K + k0 + soff]);
    }
    for (int i = 0; i < 4; i++) {
      int p = w * 4 + i;
      async_cp16(&Bs[p * 512], &Bt[(size_t)(n0 + p * 8 + r8) * K + k0 + soff]);
    }
    __syncthreads();  // barrier drains vmcnt -> LDS visible

    for (int ks = 0; ks < 2; ks++) {
      const int off = ks ? off1 : off0;
      bf16x8 af[4], bfr[4];
      for (int mt = 0; mt < 4; mt++)
        af[mt] = *(const bf16x8*)&As[(wm * 64 + mt * 16 + l15) * 64 + off];
      for (int nt = 0; nt < 4; nt++)
        bfr[nt] = *(const bf16x8*)&Bs[(wn * 64 + nt * 16 + l15) * 64 + off];
      for (int mt = 0; mt < 4; mt++)
        for (int nt = 0; nt < 4; nt++)
          acc[mt][nt] = MFMA16(af[mt], bfr[nt], acc[mt][nt]);
    }
  }

  // epilogue: C/D layout row=(lane>>4)*4+r, col=lane&15
  for (int mt = 0; mt < 4; mt++) {
    for (int nt = 0; nt < 4; nt++) {
      int gn = n0 + wn * 64 + nt * 16 + l15;
      float bb = bias[gn];
      for (int r = 0; r < 4; r++) {
        int gm = m0 + wm * 64 + mt * 16 + g * 4 + r;
        float v = (acc[mt][nt][r] + bb) * scale;
        if constexpr (SPLIT_OUT) {
          int b = gm >> 11, t = gm & 2047, h = gn >> 6, d = gn & 63;
          ((bf16*)args.out[z])[(size_t)((b * Hn + h) * Tn + t) * Dn + d] = (bf16)v;
        } else {
          ((float*)args.out[z])[(size_t)gm * Cn + gn] = v;
        }
      }
    }
  }
}

// ---------------- Flash attention v3: S^T = K Q^T, O^T = V^T P^T ----------------
// Block: 128 Q rows (4 waves x 32), KV tile 64. 512 blocks, XCD-swizzled so all
// q-blocks of a (b,h) share an XCD's L2. K staged async+swizzled, V transposed
// +swizzled, P via wave-private padded LDS rows.
constexpr int LDP = 72;  // Pt row stride (uniform bank spread on reads)

__global__ __launch_bounds__(256) void attn_kernel(const bf16* __restrict__ Qh,
                                                   const bf16* __restrict__ Kh,
                                                   const bf16* __restrict__ Vh,
                                                   bf16* __restrict__ AO) {
  __shared__ bf16 Ks[64 * 64];    // [kv][d], chunk-swizzled
  __shared__ bf16 Vt[64 * 64];    // [d][kv], chunk-swizzled
  __shared__ bf16 Pt[128 * LDP];  // [q][kv], wave-private rows

  const int tid = threadIdx.x;
  const int w = tid >> 6, lane = tid & 63;
  const int g = lane >> 4, l15 = lane & 15;
  const int id = blockIdx.x;
  const int bh = id & 31;          // linear%8 == bh%8 -> same-bh blocks share XCD
  const int q0 = (id >> 5) * 128;
  const size_t hb = (size_t)bh * Tn * Dn;
  const int r8 = lane >> 3, c8 = lane & 7;
  const int soff = (c8 ^ r8) << 3;
  const int kk = l15 & 7;
  const int off0 = (g ^ kk) << 3;
  const int off1 = ((4 + g) ^ kk) << 3;

  // Q fragments from global: lane (g,l15) of q-tile qt holds Q[q][g*8..] (B-operand of S^T)
  bf16x8 qf[2][2];
  for (int qt = 0; qt < 2; qt++) {
    const bf16* qp = Qh + hb + (size_t)(q0 + w * 32 + qt * 16 + l15) * Dn;
    qf[qt][0] = *(const bf16x8*)(qp + g * 8);
    qf[qt][1] = *(const bf16x8*)(qp + 32 + g * 8);
  }

  f32x4 o[2][4] = {};
  float m_run[2] = {-1e30f, -1e30f}, l_run[2] = {0.f, 0.f};

  for (int kt = 0; kt < Tn / 64; kt++) {
    const int t0 = kt * 64;
    __syncthreads();
    // K tile async, source columns XOR-swizzled by row
    for (int i = 0; i < 2; i++) {
      int p = w * 2 + i;
      async_cp16(&Ks[p * 512], &Kh[hb + (size_t)(t0 + p * 8 + r8) * Dn + soff]);
    }
    // V tile transposed -> Vt[d][kv], chunk-swizzled by d&7
    for (int i = 0; i < 2; i++) {
      int e = i * 256 + tid;
      int tv = e & 63, d8 = (e >> 6) << 3;
      uint4 raw = *(const uint4*)&Vh[hb + (size_t)(t0 + tv) * Dn + d8];
      const bf16* pv = (const bf16*)&raw;
      int hi = tv >> 3, lo = tv & 7;
      for (int j = 0; j < 8; j++)
        Vt[(d8 + j) * 64 + (((hi ^ j)) << 3) + lo] = pv[j];
    }
    __syncthreads();

    // S^T[kv][q]: A = K-frag (reused across 2 q-tiles), B = Q-frag (regs)
    f32x4 s[2][4] = {};
    for (int nt = 0; nt < 4; nt++) {
      const bf16* kp = &Ks[(nt * 16 + l15) * 64];
      bf16x8 kf0 = *(const bf16x8*)(kp + off0);
      bf16x8 kf1 = *(const bf16x8*)(kp + off1);
      for (int qt = 0; qt < 2; qt++) {
        s[qt][nt] = MFMA16(kf0, qf[qt][0], s[qt][nt]);
        s[qt][nt] = MFMA16(kf1, qf[qt][1], s[qt][nt]);
      }
    }

    // online softmax over kv (regs + g-groups); per-lane scalar stats per q-tile
    for (int qt = 0; qt < 2; qt++) {
      float mx = s[qt][0][0];
      for (int nt = 0; nt < 4; nt++)
        for (int r = 0; r < 4; r++) mx = fmaxf(mx, s[qt][nt][r]);
      mx = fmaxf(mx, __shfl_xor(mx, 16));
      mx = fmaxf(mx, __shfl_xor(mx, 32));
      float mn = fmaxf(m_run[qt], mx);
      float alpha = exp2f(m_run[qt] - mn);
      float rs = 0.f;
      for (int nt = 0; nt < 4; nt++)
        for (int r = 0; r < 4; r++) {
          float pe = exp2f(s[qt][nt][r] - mn);
          s[qt][nt][r] = pe;
          rs += pe;
        }
      rs += __shfl_xor(rs, 16);
      rs += __shfl_xor(rs, 32);
      l_run[qt] = l_run[qt] * alpha + rs;
      m_run[qt] = mn;
      for (int dt = 0; dt < 4; dt++) o[qt][dt] = o[qt][dt] * alpha;

      bf16* prow = &Pt[(size_t)(w * 32 + qt * 16 + l15) * LDP];
      for (int nt = 0; nt < 4; nt++) {
        bf16x2 p0 = {(bf16)s[qt][nt][0], (bf16)s[qt][nt][1]};
        bf16x2 p1 = {(bf16)s[qt][nt][2], (bf16)s[qt][nt][3]};
        *(bf16x2*)&prow[nt * 16 + g * 4] = p0;
        *(bf16x2*)&prow[nt * 16 + g * 4 + 2] = p1;
      }
    }

    // O^T += V^T P^T : A = V^T-frag (reused across q-tiles), B = P-frag
    for (int ks = 0; ks < 2; ks++) {
      const int offk = ks ? off1 : off0;
      bf16x8 vf[4];
      for (int dt = 0; dt < 4; dt++)
        vf[dt] = *(const bf16x8*)&Vt[(dt * 16 + l15) * 64 + offk];
      for (int qt = 0; qt < 2; qt++) {
        bf16x8 pf = *(const bf16x8*)&Pt[(size_t)(w * 32 + qt * 16 + l15) * LDP + ks * 32 + g * 8];
        for (int dt = 0; dt < 4; dt++)
          o[qt][dt] = MFMA16(vf[dt], pf, o[qt][dt]);
      }
    }
  }

  // epilogue: lane owns q rows (qt*16+l15); d = dt*16 + g*4 + r
  const int b = bh >> 4, h = bh & 15;
  for (int qt = 0; qt < 2; qt++) {
    float inv = 1.0f / l_run[qt];
    int qrow = q0 + w * 32 + qt * 16 + l15;
    bf16* orow = AO + (size_t)(b * Tn + qrow) * Cn + h * Dn;
    for (int dt = 0; dt < 4; dt++) {
      bf16x4 ov = {(bf16)(o[qt][dt][0] * inv), (bf16)(o[qt][dt][1] * inv),
                   (bf16)(o[qt][dt][2] * inv), (bf16)(o[qt][dt][3] * inv)};
      *(bf16x4*)&orow[dt * 16 + g * 4] = ov;
    }
  }
}

extern "C" void kernel_launch(void* const* d_in, const int* in_sizes, int n_in,
                              void* d_out, int out_size, void* d_ws, size_t ws_size,
                              hipStream_t stream) {
  const float* query = (const float*)d_in[0];
  const float* key   = (const float*)d_in[1];
  const float* value = (const float*)d_in[2];
  const float* Wq = (const float*)d_in[3];
  const float* bq = (const float*)d_in[4];
  const float* Wk = (const float*)d_in[5];
  const float* bk = (const float*)d_in[6];
  const float* Wv = (const float*)d_in[7];
  const float* bv = (const float*)d_in[8];
  const float* Wo = (const float*)d_in[9];
  const float* bo = (const float*)d_in[10];

  bf16* p = (bf16*)d_ws;
  bf16* WqT = p; p += WSZ;
  bf16* WkT = p; p += WSZ;
  bf16* WvT = p; p += WSZ;
  bf16* WoT = p; p += WSZ;
  bf16* Xbf = p; p += 3 * XSZ;   // bf16 activations; first third reused as AO later
  bf16* Qh = p; p += XSZ;
  bf16* Kh = p; p += XSZ;
  bf16* Vh = p; p += XSZ;
  bf16* AO = Xbf;                // Xbf dead after QKV GEMM

  TransArgs ta;
  ta.W[0] = Wq; ta.W[1] = Wk; ta.W[2] = Wv; ta.W[3] = Wo;
  ta.Wt[0] = WqT; ta.Wt[1] = WkT; ta.Wt[2] = WvT; ta.Wt[3] = WoT;
  transpose_convert<<<dim3(32, 32, 4), dim3(32, 8), 0, stream>>>(ta);

  ConvArgs ca;
  ca.src[0] = query; ca.src[1] = key; ca.src[2] = value;
  convert_bf16<<<dim3(XSZ / 2048, 3), 256, 0, stream>>>(ca, Xbf);

  GemmArgs ga;
  ga.A[0] = Xbf; ga.A[1] = Xbf + XSZ; ga.A[2] = Xbf + 2 * XSZ;
  ga.Bt[0] = WqT;  ga.Bt[1] = WkT; ga.Bt[2] = WvT;
  ga.bias[0] = bq; ga.bias[1] = bk; ga.bias[2] = bv;
  ga.out[0] = Qh;  ga.out[1] = Kh;  ga.out[2] = Vh;
  ga.scale[0] = 0.125f * LOG2E; ga.scale[1] = 1.0f; ga.scale[2] = 1.0f;
  gemm_kernel<true><<<dim3(Cn / 128, Mn / 128, 3), 256, 0, stream>>>(ga, Cn);

  attn_kernel<<<dim3(512), 256, 0, stream>>>(Qh, Kh, Vh, AO);

  GemmArgs gb;
  gb.A[0] = AO; gb.Bt[0] = WoT; gb.bias[0] = bo; gb.out[0] = d_out; gb.scale[0] = 1.0f;
  gb.A[1] = gb.A[2] = nullptr; gb.Bt[1] = gb.Bt[2] = nullptr;
  gb.bias[1] = gb.bias[2] = nullptr; gb.out[1] = gb.out[2] = nullptr;
  gb.scale[1] = gb.scale[2] = 1.0f;
  gemm_kernel<false><<<dim3(Cn / 128, Mn / 128, 1), 256, 0, stream>>>(gb, Cn);
}